// Round 5
// baseline (106.527 us; speedup 1.0000x reference)
//
#include <hip/hip_runtime.h>
#include <stdint.h>

typedef _Float16 f16;
typedef __attribute__((ext_vector_type(8))) _Float16 f16x8;
typedef __attribute__((ext_vector_type(4))) float    f32x4;

constexpr int BROWS = 16384;
constexpr int NTASK = 3;

// ---- packed-weight layout in d_ws (f16 elements) ----
constexpr int OFF_CW1 = 0;                       // [256][480]
constexpr int OFF_CW2 = OFF_CW1 + 256 * 480;     // [128][256]
constexpr int OFF_COW = OFF_CW2 + 128 * 256;     // [512][128]
constexpr int OFF_EW1 = OFF_COW + 512 * 128;     // [1024][480]  (4 experts x 256)
constexpr int OFF_EW2 = OFF_EW1 + 1024 * 480;    // [512][256]   (4 experts x 128)
constexpr int OFF_FMW = OFF_EW2 + 512 * 256;     // [16][480]
constexpr int OFF_GW  = OFF_FMW + 16 * 480;      // [16][480]
constexpr int OFF_CTW = OFF_GW  + 16 * 480;      // [64][64]
constexpr int PACK_TOTAL = OFF_CTW + 64 * 64;    // 863,232 f16 = 1.73 MB

// ---------------------------------------------------------------------------
// Kernel 0: pack ALL weights to f16, transposed [N][K], zero-padded. 1 launch.
// ---------------------------------------------------------------------------
__global__ __launch_bounds__(256)
void pack_all(const float* __restrict__ cW1, const float* __restrict__ cW2,
              const float* __restrict__ coW, const float* __restrict__ expW1,
              const float* __restrict__ expW2, const float* __restrict__ fmW,
              const float* __restrict__ gateW, const float* __restrict__ contW,
              f16* __restrict__ wp)
{
    const int idx = blockIdx.x * 256 + threadIdx.x;
    if (idx >= PACK_TOTAL) return;
    float v = 0.f;
    if (idx < OFF_CW2) {                       // cW1 (464,256)
        const int l = idx - OFF_CW1, n = l / 480, k = l % 480;
        if (k < 464) v = cW1[k * 256 + n];
    } else if (idx < OFF_COW) {                // cW2 (256,128)
        const int l = idx - OFF_CW2, n = l / 256, k = l % 256;
        v = cW2[k * 128 + n];
    } else if (idx < OFF_EW1) {                // coW (128,464), Npad 512
        const int l = idx - OFF_COW, n = l / 128, k = l % 128;
        if (n < 464) v = coW[k * 464 + n];
    } else if (idx < OFF_EW2) {                // expW1 (4,464,256)
        const int l = idx - OFF_EW1, n = l / 480, k = l % 480;
        const int e = n >> 8, nn = n & 255;
        if (k < 464) v = expW1[(e * 464 + k) * 256 + nn];
    } else if (idx < OFF_FMW) {                // expW2 (4,256,128)
        const int l = idx - OFF_EW2, n = l / 256, k = l % 256;
        const int e = n >> 7, nn = n & 127;
        v = expW2[(e * 256 + k) * 128 + nn];
    } else if (idx < OFF_GW) {                 // fmW (464,10) -> [16][480]
        const int l = idx - OFF_FMW, c = l / 480, k = l % 480;
        if (c < 10 && k < 464) v = fmW[k * 10 + c];
    } else if (idx < OFF_CTW) {                // gateW (3,464,4) -> [16][480]
        const int l = idx - OFF_GW, c = l / 480, k = l % 480;
        if (c < 12 && k < 464) {
            const int tt = c >> 2, e = c & 3;
            v = gateW[(tt * 464 + k) * 4 + e];
        }
    } else {                                   // contW (64,64) -> [64][64]
        const int l = idx - OFF_CTW, n = l / 64, k = l % 64;
        v = contW[k * 64 + n];
    }
    wp[idx] = (f16)v;
}

// ---------------------------------------------------------------------------
// wave-level GEMM helper: acc[MF][NF] (+)= A_lds @ B_glb^T over KS k-steps.
// A-frag: lane (l&15)=row, (l>>4)*8=k-chunk. B from global [N][ldb] f16.
// D layout: col = l&15, row = (l>>4)*4 + reg (HW-verified, rounds 2/4 pass).
// ---------------------------------------------------------------------------
template<int MF, int NF, int KS, int LDA>
__device__ __forceinline__ void wave_gemm(
    const f16* __restrict__ As, int arow0,
    const f16* __restrict__ Bg, int bcol0, int ldb,
    f32x4 (&acc)[MF][NF], int lane)
{
    const int g = lane >> 4, rr = lane & 15;
#pragma unroll
    for (int kb = 0; kb < KS; ++kb) {
        const int ko = kb * 32 + g * 8;
        f16x8 bf[NF];
#pragma unroll
        for (int j = 0; j < NF; ++j)
            bf[j] = *(const f16x8*)(Bg + (long)(bcol0 + j * 16 + rr) * ldb + ko);
#pragma unroll
        for (int i = 0; i < MF; ++i) {
            const f16x8 af = *(const f16x8*)(As + (arow0 + i * 16 + rr) * LDA + ko);
#pragma unroll
            for (int j = 0; j < NF; ++j)
                acc[i][j] = __builtin_amdgcn_mfma_f32_16x16x32_f16(
                    af, bf[j], acc[i][j], 0, 0, 0);
        }
    }
}

// ---------------------------------------------------------------------------
// Kernel 1: entire MMoE forward, 64 rows/block, 256 blocks, 8 waves/block.
// ---------------------------------------------------------------------------
__global__ __launch_bounds__(512, 1)
void mmoe_fused(const int* __restrict__ disc, const float* __restrict__ cf,
                const float* __restrict__ e0p, const float* __restrict__ e1p,
                const float* __restrict__ e2p, const float* __restrict__ e3p,
                const float* __restrict__ e4p, const float* __restrict__ e5p,
                const float* __restrict__ e6p, const float* __restrict__ e7p,
                const float* __restrict__ contB, const float* __restrict__ cb1,
                const float* __restrict__ cb2, const float* __restrict__ cob,
                const float* __restrict__ expb1, const float* __restrict__ expb2,
                const float* __restrict__ gateB, const float* __restrict__ taskW,
                const float* __restrict__ taskB, const float* __restrict__ logv,
                const f16* __restrict__ wp, float* __restrict__ out)
{
    __shared__ f16   sh_x [64][488];   // x, later h (cols 464..487 zero)
    __shared__ f16   sh_c1[64][264];   // c1 / e1
    __shared__ f16   sh_c2[64][136];   // c2 (cf staging aliases this)
    __shared__ float sh_g [64][12];    // gate probs
    __shared__ float sh_part[8][64][3];
    __shared__ float sh_fm[64];
    __shared__ const float* stabs[8];

    const int t = threadIdx.x;
    const int lane = t & 63, wave = t >> 6;       // wave 0..7
    const int g = lane >> 4, rr = lane & 15;
    const long r0 = (long)blockIdx.x * 64;

    const f16* cW1p = wp + OFF_CW1;
    const f16* cW2p = wp + OFF_CW2;
    const f16* coWp = wp + OFF_COW;
    const f16* eW1p = wp + OFF_EW1;
    const f16* eW2p = wp + OFF_EW2;
    const f16* fmWp = wp + OFF_FMW;
    const f16* gWp  = wp + OFF_GW;
    const f16* ctWp = wp + OFF_CTW;

    if (t == 0) {
        stabs[0] = e0p; stabs[1] = e1p; stabs[2] = e2p; stabs[3] = e3p;
        stabs[4] = e4p; stabs[5] = e5p; stabs[6] = e6p; stabs[7] = e7p;
    }
    __syncthreads();

    // ---- P0a: zero-pad x, gather embeddings, stage cf as f16 ----
    f16* cfp = (f16*)&sh_c2[0][0];                       // [64][72]
    for (int i = t; i < 64 * 24; i += 512) sh_x[i / 24][464 + i % 24] = (f16)0.f;
    {   // one (row, table) pair per thread
        const int r = t >> 3, tab = t & 7;
        const long fi = disc[(r0 + r) * 8 + tab];
        const float* src = stabs[tab] + fi * 50;
        f16* dst = &sh_x[r][tab * 50];
#pragma unroll
        for (int q = 0; q < 25; ++q) {
            const float2 v = *(const float2*)(src + q * 2);
            dst[q * 2] = (f16)v.x; dst[q * 2 + 1] = (f16)v.y;
        }
    }
    for (int i = t; i < 64 * 16; i += 512) {             // cf [64][64] f32 -> f16
        const int r = i >> 4, q = i & 15;
        const float4 v = *(const float4*)(cf + (r0 + r) * 64 + q * 4);
        f16* dst = cfp + r * 72 + q * 4;
        dst[0] = (f16)v.x; dst[1] = (f16)v.y; dst[2] = (f16)v.z; dst[3] = (f16)v.w;
    }
    __syncthreads();

    // ---- P0b: cont = relu(cf @ contW + b) -> sh_x[:,400:464]  (2M x 4N) ----
    {
        const int wm = wave >> 2, wn = wave & 3;
        f32x4 acc[2][1] = {};
        wave_gemm<2, 1, 2, 72>(cfp, wm * 32, ctWp, wn * 16, 64, acc, lane);
        const int col = wn * 16 + rr;
        const float bv = contB[col];
#pragma unroll
        for (int i = 0; i < 2; ++i)
#pragma unroll
            for (int rx = 0; rx < 4; ++rx)
                sh_x[wm * 32 + i * 16 + g * 4 + rx][400 + col] =
                    (f16)fmaxf(acc[i][0][rx] + bv, 0.f);
    }
    __syncthreads();

    // ---- P0c: FM (waves 0-3) + c1 (all waves, read-only on sh_x) ----
    if (wave < 4) {  // FM: xe = x @ fmW; fm = .5*((Σxe)^2 - Σxe^2)
        f32x4 a[1][1] = {};
        wave_gemm<1, 1, 15, 488>(&sh_x[0][0], wave * 16, fmWp, 0, 480, a, lane);
#pragma unroll
        for (int rx = 0; rx < 4; ++rx) {
            const float v = a[0][0][rx];
            float s = v, ss = v * v;
#pragma unroll
            for (int off = 1; off < 16; off <<= 1) {
                s += __shfl_xor(s, off, 64); ss += __shfl_xor(ss, off, 64);
            }
            if (rr == 0) sh_fm[wave * 16 + g * 4 + rx] = 0.5f * (s * s - ss);
        }
    }
    {   // c1 = relu(x @ cW1 + cb1), 32 cols per wave
        f32x4 acc[4][2] = {};
        wave_gemm<4, 2, 15, 488>(&sh_x[0][0], 0, cW1p, wave * 32, 480, acc, lane);
#pragma unroll
        for (int j = 0; j < 2; ++j) {
            const int col = wave * 32 + j * 16 + rr;
            const float bv = cb1[col];
#pragma unroll
            for (int i = 0; i < 4; ++i)
#pragma unroll
                for (int rx = 0; rx < 4; ++rx)
                    sh_c1[i * 16 + g * 4 + rx][col] =
                        (f16)fmaxf(acc[i][j][rx] + bv, 0.f);
        }
    }
    __syncthreads();

    // ---- P2: c2 = relu(c1 @ cW2 + cb2), 16 cols per wave ----
    {
        f32x4 acc[4][1] = {};
        wave_gemm<4, 1, 8, 264>(&sh_c1[0][0], 0, cW2p, wave * 16, 256, acc, lane);
        const int col = wave * 16 + rr;
        const float bv = cb2[col];
#pragma unroll
        for (int i = 0; i < 4; ++i)
#pragma unroll
            for (int rx = 0; rx < 4; ++rx)
                sh_c2[i * 16 + g * 4 + rx][col] =
                    (f16)fmaxf(acc[i][0][rx] + bv, 0.f);
    }
    __syncthreads();

    // ---- P3: h = x + (c2 @ coW + cob) + fm  (in-place into sh_x) ----
    {
        f32x4 acc[4][4] = {};
        wave_gemm<4, 4, 4, 136>(&sh_c2[0][0], 0, coWp, wave * 64, 128, acc, lane);
#pragma unroll
        for (int j = 0; j < 4; ++j) {
            const int col = wave * 64 + j * 16 + rr;
            if (col < 464) {
                const float bv = cob[col];
#pragma unroll
                for (int i = 0; i < 4; ++i)
#pragma unroll
                    for (int rx = 0; rx < 4; ++rx) {
                        const int row = i * 16 + g * 4 + rx;
                        const float v = acc[i][j][rx] + bv +
                                        (float)sh_x[row][col] + sh_fm[row];
                        sh_x[row][col] = (f16)v;
                    }
            }
        }
    }
    __syncthreads();

    // ---- gates: softmax_e(h @ gateW + gb) -> sh_g (waves 0-3) ----
    if (wave < 4) {
        f32x4 a[1][1] = {};
        wave_gemm<1, 1, 15, 488>(&sh_x[0][0], wave * 16, gWp, 0, 480, a, lane);
        const float gb = (rr < 12) ? gateB[rr] : 0.f;
#pragma unroll
        for (int rx = 0; rx < 4; ++rx) {
            const float v = a[0][0][rx] + gb;
            float m = fmaxf(v, __shfl_xor(v, 1, 64));
            m = fmaxf(m, __shfl_xor(m, 2, 64));
            const float p = __expf(v - m);
            float s = p + __shfl_xor(p, 1, 64);
            s += __shfl_xor(s, 2, 64);
            if (rr < 12) sh_g[wave * 16 + g * 4 + rx][rr] = p / s;
        }
    }
    __syncthreads();

    // ---- experts: e1 = relu(h@W1+b1); oacc += g_e * eo . taskW (per-lane) ----
    float tw[3];
#pragma unroll
    for (int tt = 0; tt < 3; ++tt) tw[tt] = taskW[tt * 128 + wave * 16 + rr];

    float oacc[4][4][3];
#pragma unroll
    for (int i = 0; i < 4; ++i)
#pragma unroll
        for (int rx = 0; rx < 4; ++rx)
#pragma unroll
            for (int tt = 0; tt < 3; ++tt) oacc[i][rx][tt] = 0.f;

#pragma unroll
    for (int e = 0; e < 4; ++e) {
        {   // e1 -> sh_c1 (32 cols per wave)
            f32x4 acc[4][2] = {};
            wave_gemm<4, 2, 15, 488>(&sh_x[0][0], 0, eW1p + e * (256 * 480),
                                     wave * 32, 480, acc, lane);
#pragma unroll
            for (int j = 0; j < 2; ++j) {
                const int col = wave * 32 + j * 16 + rr;
                const float bv = expb1[e * 256 + col];
#pragma unroll
                for (int i = 0; i < 4; ++i)
#pragma unroll
                    for (int rx = 0; rx < 4; ++rx)
                        sh_c1[i * 16 + g * 4 + rx][col] =
                            (f16)fmaxf(acc[i][j][rx] + bv, 0.f);
            }
        }
        __syncthreads();
        {   // eo (regs only) -> gated per-lane accumulate (reduce deferred)
            f32x4 acc[4][1] = {};
            wave_gemm<4, 1, 8, 264>(&sh_c1[0][0], 0, eW2p + e * (128 * 256),
                                    wave * 16, 256, acc, lane);
            const float bv = expb2[e * 128 + wave * 16 + rr];
#pragma unroll
            for (int i = 0; i < 4; ++i)
#pragma unroll
                for (int rx = 0; rx < 4; ++rx) {
                    const int row = i * 16 + g * 4 + rx;
                    const float v0 = acc[i][0][rx] + bv;
#pragma unroll
                    for (int tt = 0; tt < 3; ++tt)
                        oacc[i][rx][tt] += sh_g[row][tt * 4 + e] * (v0 * tw[tt]);
                }
        }
        __syncthreads();
    }

    // ---- single deferred 16-lane reduce, then cross-wave sum ----
#pragma unroll
    for (int i = 0; i < 4; ++i)
#pragma unroll
        for (int rx = 0; rx < 4; ++rx)
#pragma unroll
            for (int tt = 0; tt < 3; ++tt) {
                float s = oacc[i][rx][tt];
#pragma unroll
                for (int off = 1; off < 16; off <<= 1)
                    s += __shfl_xor(s, off, 64);
                if (rr == 0)
                    sh_part[wave][i * 16 + g * 4 + rx][tt] = s;
            }
    __syncthreads();
    if (t < 64 * 3) {
        const int row = t / 3, tt = t - row * 3;
        float s = taskB[tt];
#pragma unroll
        for (int w = 0; w < 8; ++w) s += sh_part[w][row][tt];
        out[(r0 + row) * 3 + tt] = s;
    }
    if (blockIdx.x == 0 && t < NTASK) out[(long)BROWS * 3 + t] = logv[t];
}

// ---------------------------------------------------------------------------
extern "C" void kernel_launch(void* const* d_in, const int* in_sizes, int n_in,
                              void* d_out, int out_size, void* d_ws, size_t ws_size,
                              hipStream_t stream)
{
    (void)in_sizes; (void)n_in; (void)out_size; (void)ws_size;

    const int*   disc  = (const int*)  d_in[0];
    const float* cf    = (const float*)d_in[1];
    const float* emb0  = (const float*)d_in[2];
    const float* emb1  = (const float*)d_in[3];
    const float* emb2  = (const float*)d_in[4];
    const float* emb3  = (const float*)d_in[5];
    const float* emb4  = (const float*)d_in[6];
    const float* emb5  = (const float*)d_in[7];
    const float* emb6  = (const float*)d_in[8];
    const float* emb7  = (const float*)d_in[9];
    const float* contW = (const float*)d_in[10];
    const float* contB = (const float*)d_in[11];
    const float* fmW   = (const float*)d_in[12];
    const float* cW1   = (const float*)d_in[13];
    const float* cb1   = (const float*)d_in[14];
    const float* cW2   = (const float*)d_in[15];
    const float* cb2   = (const float*)d_in[16];
    const float* coW   = (const float*)d_in[17];
    const float* cob   = (const float*)d_in[18];
    const float* expW1 = (const float*)d_in[19];
    const float* expb1 = (const float*)d_in[20];
    const float* expW2 = (const float*)d_in[21];
    const float* expb2 = (const float*)d_in[22];
    const float* gateW = (const float*)d_in[23];
    const float* gateB = (const float*)d_in[24];
    const float* taskW = (const float*)d_in[25];
    const float* taskB = (const float*)d_in[26];
    const float* logv  = (const float*)d_in[27];

    f16* wp = (f16*)d_ws;

    pack_all<<<(PACK_TOTAL + 255) / 256, 256, 0, stream>>>(
        cW1, cW2, coW, expW1, expW2, fmW, gateW, contW, wp);

    mmoe_fused<<<BROWS / 64, 512, 0, stream>>>(
        disc, cf, emb0, emb1, emb2, emb3, emb4, emb5, emb6, emb7,
        contB, cb1, cb2, cob, expb1, expb2, gateB, taskW, taskB, logv,
        wp, (float*)d_out);
}